// Round 6
// baseline (169.027 us; speedup 1.0000x reference)
//
#include <hip/hip_runtime.h>

#define NN 25000
#define EE 400000
#define FIN 128
#define FE 16
#define CH 32
#define SLOPE 0.01f
#define PROJ_BLOCKS 391   // ceil(25000/64)
#define AUX_BLOCKS 32
#define WROW 16                        // WtL row stride in shorts (32B)
#define WTP_SHORTS (1024 * WROW + 32)  // +64B zero tail (quad-2/3 reads of last row)

typedef __attribute__((ext_vector_type(8))) short bf16x8;
typedef __attribute__((ext_vector_type(4))) float f32x4;

__device__ __forceinline__ float lrelu(float v) { return fmaxf(v, SLOPE * v); }

__device__ __forceinline__ f32x4 lrelu4(f32x4 v) {
    f32x4 s = v * SLOPE;
#if __has_builtin(__builtin_elementwise_max)
    return __builtin_elementwise_max(v, s);   // v_pk_max_f32
#else
    f32x4 r;
    r[0] = fmaxf(v[0], s[0]); r[1] = fmaxf(v[1], s[1]);
    r[2] = fmaxf(v[2], s[2]); r[3] = fmaxf(v[3], s[3]);
    return r;
#endif
}

// float -> bf16 bits, round-to-nearest-even
__device__ __forceinline__ short f2bf(float f) {
    union { float f; unsigned u; } v; v.f = f;
    unsigned r = (v.u + 0x7fffu + ((v.u >> 16) & 1u)) >> 16;
    return (short)r;
}

// ---------------- Kernel 1: fused prep
// blocks [0, PROJ_BLOCKS): h = leaky(x @ W_in + b_in) via MFMA (64 nodes/block)
// blocks [PROJ, +4): WtP[co][16] = bf16 W_edge^T row ; [+4,+32): zero aggr
__global__ void __launch_bounds__(256)
k_pre(const float* __restrict__ x, const float* __restrict__ W_in,
      const float* __restrict__ b_in, const float* __restrict__ W_edge,
      float* __restrict__ h, float* __restrict__ aggr, short* __restrict__ WtP) {
    __shared__ short Wt1[CH * 136];
    int tid = threadIdx.x;

    if (blockIdx.x >= PROJ_BLOCKS) {
        int ab = blockIdx.x - PROJ_BLOCKS;
        if (ab < 4) {
            int co = ab * 256 + tid;                       // 0..1023
            short row[WROW] __attribute__((aligned(16)));
#pragma unroll
            for (int k = 0; k < 16; k++) row[k] = f2bf(W_edge[k * 1024 + co]);
            uint4* dstp = (uint4*)(WtP + co * WROW);       // co*32B, 16B-aligned
            dstp[0] = ((uint4*)row)[0]; dstp[1] = ((uint4*)row)[1];
            if (ab == 0 && tid < 32) WtP[1024 * WROW + tid] = 0;   // tail pad
        } else {
            int t = (ab - 4) * 256 + tid;
            float4 z = make_float4(0.f, 0.f, 0.f, 0.f);
            for (int i = t; i < NN * CH / 4; i += (AUX_BLOCKS - 4) * 256)
                ((float4*)aggr)[i] = z;
        }
        return;
    }

    // ---- input projection ----
#pragma unroll
    for (int i = 0; i < 16; i++) {
        int id = tid + 256 * i;           // id = k*32 + c
        int k = id >> 5, c = id & 31;
        Wt1[c * 136 + k] = f2bf(W_in[id]);
    }
    __syncthreads();

    int wave = tid >> 6, lane = tid & 63;
    int n16 = lane & 15, quad = lane >> 4;
    int node0 = blockIdx.x * 64 + wave * 16;

    f32x4 D[2];
#pragma unroll
    for (int ch = 0; ch < 2; ch++) {
        float bb = b_in[ch * 16 + n16];
        D[ch] = (f32x4){bb, bb, bb, bb};
    }
    int arow = node0 + n16; if (arow >= NN) arow = NN - 1;
#pragma unroll
    for (int kb = 0; kb < 4; kb++) {
        const float4* xp = (const float4*)(x + (size_t)arow * FIN + kb * 32 + quad * 8);
        float4 xa = xp[0], xb = xp[1];
        bf16x8 A = (bf16x8){f2bf(xa.x), f2bf(xa.y), f2bf(xa.z), f2bf(xa.w),
                            f2bf(xb.x), f2bf(xb.y), f2bf(xb.z), f2bf(xb.w)};
#pragma unroll
        for (int ch = 0; ch < 2; ch++) {
            bf16x8 B = *(const bf16x8*)&Wt1[(ch * 16 + n16) * 136 + kb * 32 + quad * 8];
            D[ch] = __builtin_amdgcn_mfma_f32_16x16x32_bf16(A, B, D[ch], 0, 0, 0);
        }
    }
#pragma unroll
    for (int ch = 0; ch < 2; ch++)
#pragma unroll
        for (int r = 0; r < 4; r++) {
            int nn = node0 + quad * 4 + r;
            if (nn < NN) h[(size_t)nn * CH + ch * 16 + n16] = lrelu(D[ch][r]);
        }
}

// ---------------- Kernel 2: fused edge-NN (MFMA, bias via C-splat) + matvec + scatter
// LDS: WtL 32.8KB + hsT 16.9KB + bT 4.3KB = 54.1KB -> 3 blocks/CU (12 waves)
__global__ void __launch_bounds__(256, 3)
k_edge(const short* __restrict__ WtP,    // [1024][16] bf16 (+32-short zero tail)
       const float* __restrict__ ea,     // [EE][16] f32
       const float* __restrict__ b_edge, // [1024] f32
       const int* __restrict__ src,
       const int* __restrict__ dst,
       const float* __restrict__ h,
       float* __restrict__ aggr) {
    __shared__ short WtL[WTP_SHORTS];    // 32832 B
    __shared__ float hsT[CH * 132];      // 16896 B, hsT[c][e]
    __shared__ float bT[16 * 68];        // 4352 B, bT[n16][cb], stride 68

    int tid = threadIdx.x;
    int e0 = blockIdx.x * 128;

    // stage WtL: 2052 uint4 vector copies
#pragma unroll
    for (int j = 0; j < 9; j++) {
        int idx = tid + 256 * j;
        if (idx < WTP_SHORTS / 8) ((uint4*)WtL)[idx] = ((const uint4*)WtP)[idx];
    }
    // stage bT transposed: bT[co&15][co>>4]
#pragma unroll
    for (int i = 0; i < 4; i++) {
        int co = tid + 256 * i;
        bT[(co & 15) * 68 + (co >> 4)] = b_edge[co];
    }
    // stage hsT transposed: thread = (edge e=tid>>1, half=tid&1)
    {
        int e = tid >> 1, half = tid & 1;
        int s = src[e0 + e];
        const float4* hp = (const float4*)(h + (size_t)s * CH + half * 16);
        float vv[16] __attribute__((aligned(16)));
        *(float4*)&vv[0] = hp[0]; *(float4*)&vv[4] = hp[1];
        *(float4*)&vv[8] = hp[2]; *(float4*)&vv[12] = hp[3];
#pragma unroll
        for (int j = 0; j < 16; j++) hsT[(half * 16 + j) * 132 + e] = vv[j];
    }
    __syncthreads();

    int wave = tid >> 6, lane = tid & 63;
    int n16 = lane & 15, quad = lane >> 4;
    int t0 = wave * 32, t1 = t0 + 16;

    // A fragments: quads 0,1 = ea (f2bf in regs); quads 2,3 = zero K-pad
    bf16x8 A0 = (bf16x8){0,0,0,0,0,0,0,0}, A1 = A0;
    if (quad < 2) {
        const float4* p0 = (const float4*)(ea + (size_t)(e0 + t0 + n16) * FE + quad * 8);
        float4 a = p0[0], b = p0[1];
        A0 = (bf16x8){f2bf(a.x), f2bf(a.y), f2bf(a.z), f2bf(a.w),
                      f2bf(b.x), f2bf(b.y), f2bf(b.z), f2bf(b.w)};
        const float4* p1 = (const float4*)(ea + (size_t)(e0 + t1 + n16) * FE + quad * 8);
        a = p1[0]; b = p1[1];
        A1 = (bf16x8){f2bf(a.x), f2bf(a.y), f2bf(a.z), f2bf(a.w),
                      f2bf(b.x), f2bf(b.y), f2bf(b.z), f2bf(b.w)};
    }

    f32x4 m0[2], m1[2];
    m0[0] = (f32x4){0,0,0,0}; m0[1] = m0[0]; m1[0] = m0[0]; m1[1] = m0[0];

    // imm-offset bases
    const short* Bbase = WtL + n16 * WROW + quad * 8;   // + cb*(16*WROW) imm
    const float* bTb = bT + n16 * 68;                   // + cb imm
    const float* h0b = hsT + t0 + quad * 4;             // + c*132 imm
    const float* h1b = hsT + t1 + quad * 4;

#pragma unroll
    for (int c4 = 0; c4 < 8; c4++) {
#pragma unroll
        for (int cc = 0; cc < 4; cc++) {
            int c = c4 * 4 + cc;
            f32x4 hc0 = *(const f32x4*)(h0b + c * 132);
            f32x4 hc1 = *(const f32x4*)(h1b + c * 132);
#pragma unroll
            for (int oh = 0; oh < 2; oh++) {
                int cb = c * 2 + oh;
                bf16x8 B = *(const bf16x8*)(Bbase + cb * (16 * WROW));
                float bb = bTb[cb];
                f32x4 Cb = (f32x4){bb, bb, bb, bb};
                f32x4 D0 = __builtin_amdgcn_mfma_f32_16x16x32_bf16(A0, B, Cb, 0, 0, 0);
                f32x4 D1 = __builtin_amdgcn_mfma_f32_16x16x32_bf16(A1, B, Cb, 0, 0, 0);
                m0[oh] += hc0 * lrelu4(D0);              // v_pk_fma_f32
                m1[oh] += hc1 * lrelu4(D1);
            }
        }
    }

    // scatter: lane holds msg for edges (tX + quad*4 + r), col o = oh*16 + n16
#pragma unroll
    for (int r = 0; r < 4; r++) {
        int ed0 = dst[e0 + t0 + quad * 4 + r];
        int ed1 = dst[e0 + t1 + quad * 4 + r];
#pragma unroll
        for (int oh = 0; oh < 2; oh++) {
            unsafeAtomicAdd(&aggr[(size_t)ed0 * CH + oh * 16 + n16], m0[oh][r]);
            unsafeAtomicAdd(&aggr[(size_t)ed1 * CH + oh * 16 + n16], m1[oh][r]);
        }
    }
}

// ---------------- Kernel 3 (MFMA): out = leaky(aggr + h@W_root + b_conv) @ W_out + b_out
__global__ void __launch_bounds__(256)
k_node(const float* __restrict__ aggr,
       const float* __restrict__ h,
       const float* __restrict__ W_root,
       const float* __restrict__ b_conv,
       const float* __restrict__ W_out,
       const float* __restrict__ b_out,
       float* __restrict__ out) {
    __shared__ short WrB[CH * 40];   // W_root^T bf16: [o][c], stride 40 shorts
    __shared__ float WoS[CH];
    int tid = threadIdx.x;
    if (tid < 128) {
        int o = tid >> 2, c0 = (tid & 3) * 8;
        short tmp[8] __attribute__((aligned(16)));
#pragma unroll
        for (int j = 0; j < 8; j++) tmp[j] = f2bf(W_root[(c0 + j) * CH + o]);
        *(bf16x8*)&WrB[o * 40 + c0] = *(bf16x8*)tmp;
    } else if (tid < 160) {
        WoS[tid - 128] = W_out[tid - 128];
    }
    __syncthreads();

    int wave = tid >> 6, lane = tid & 63;
    int n16 = lane & 15, quad = lane >> 4;
    int node0 = blockIdx.x * 64 + wave * 16;

    int arow = node0 + n16; if (arow >= NN) arow = NN - 1;
    const float4* hp = (const float4*)(h + (size_t)arow * CH + quad * 8);
    float4 ha = hp[0], hb = hp[1];
    bf16x8 A = (bf16x8){f2bf(ha.x), f2bf(ha.y), f2bf(ha.z), f2bf(ha.w),
                        f2bf(hb.x), f2bf(hb.y), f2bf(hb.z), f2bf(hb.w)};
    float bc0 = b_conv[n16], bc1 = b_conv[16 + n16];
    f32x4 C0, C1;
#pragma unroll
    for (int r = 0; r < 4; r++) {
        int nr = node0 + quad * 4 + r; int cr = (nr < NN) ? nr : NN - 1;
        C0[r] = aggr[(size_t)cr * CH + n16] + bc0;
        C1[r] = aggr[(size_t)cr * CH + 16 + n16] + bc1;
    }
    bf16x8 B0 = *(const bf16x8*)&WrB[n16 * 40 + quad * 8];
    bf16x8 B1 = *(const bf16x8*)&WrB[(16 + n16) * 40 + quad * 8];
    f32x4 D0 = __builtin_amdgcn_mfma_f32_16x16x32_bf16(A, B0, C0, 0, 0, 0);
    f32x4 D1 = __builtin_amdgcn_mfma_f32_16x16x32_bf16(A, B1, C1, 0, 0, 0);

    float w0 = WoS[n16], w1 = WoS[16 + n16];
    f32x4 p;
#pragma unroll
    for (int r = 0; r < 4; r++)
        p[r] = lrelu(D0[r]) * w0 + lrelu(D1[r]) * w1;
#pragma unroll
    for (int mk = 1; mk < 16; mk <<= 1) {
#pragma unroll
        for (int r = 0; r < 4; r++) p[r] += __shfl_xor(p[r], mk, 64);
    }
    if (n16 == 0) {
        float bo = b_out[0];
#pragma unroll
        for (int r = 0; r < 4; r++) {
            int nr = node0 + quad * 4 + r;
            if (nr < NN) out[nr] = p[r] + bo;
        }
    }
}

extern "C" void kernel_launch(void* const* d_in, const int* in_sizes, int n_in,
                              void* d_out, int out_size, void* d_ws, size_t ws_size,
                              hipStream_t stream) {
    const float* x      = (const float*)d_in[0];
    const int*   ei     = (const int*)d_in[1];
    const float* ea     = (const float*)d_in[2];
    const float* W_in   = (const float*)d_in[3];
    const float* b_in   = (const float*)d_in[4];
    const float* W_edge = (const float*)d_in[5];
    const float* b_edge = (const float*)d_in[6];
    const float* W_root = (const float*)d_in[7];
    const float* b_conv = (const float*)d_in[8];
    const float* W_out  = (const float*)d_in[9];
    const float* b_out  = (const float*)d_in[10];
    float* out  = (float*)d_out;
    float* h    = (float*)d_ws;                  // [NN*CH] f32
    float* aggr = h + (size_t)NN * CH;           // [NN*CH] f32
    short* WtP  = (short*)(aggr + (size_t)NN * CH);  // [WTP_SHORTS] bf16

    k_pre<<<PROJ_BLOCKS + AUX_BLOCKS, 256, 0, stream>>>(x, W_in, b_in, W_edge,
                                                        h, aggr, WtP);
    k_edge<<<EE / 128, 256, 0, stream>>>(WtP, ea, b_edge, ei, ei + EE, h, aggr);
    k_node<<<PROJ_BLOCKS, 256, 0, stream>>>(aggr, h, W_root, b_conv, W_out, b_out, out);
}